// Round 1
// baseline (267.848 us; speedup 1.0000x reference)
//
#include <hip/hip_runtime.h>

#define NTOK   131072
#define KCODES 1024
#define DIM    64
#define BM     64
#define BN     128
#define ZS_STRIDE (BM + 4)   // 68 floats: keeps 16B alignment, spreads banks
#define ES_STRIDE (BN + 4)   // 132 floats

#define LOSS_OFF (NTOK * DIM)        // 8388608
#define IDX_OFF  (LOSS_OFF + 1)      // 8388609

// ---------------------------------------------------------------- K0: e_sq
__global__ __launch_bounds__(256) void esq_kernel(const float* __restrict__ E,
                                                  float* __restrict__ esq) {
    int c = blockIdx.x * blockDim.x + threadIdx.x;
    if (c < KCODES) {
        const float4* row = (const float4*)(E + c * DIM);
        float s = 0.f;
        #pragma unroll
        for (int i = 0; i < DIM / 4; ++i) {
            float4 v = row[i];
            s += v.x * v.x + v.y * v.y + v.z * v.z + v.w * v.w;
        }
        esq[c] = s;
    }
}

// ------------------------------------------------- K1: distances + argmin
__global__ __launch_bounds__(256) void argmin_kernel(
    const float* __restrict__ z, const float* __restrict__ E,
    const float* __restrict__ esq, float* __restrict__ idx_out) {
    __shared__ __align__(16) float zs[DIM][ZS_STRIDE];
    __shared__ __align__(16) float es[DIM][ES_STRIDE];
    __shared__ float zsq_s[BM];

    const int t = threadIdx.x;
    const int row0 = blockIdx.x * BM;

    // stage z tile, transposed [k][token]
    {
        const float4* zg = (const float4*)(z + (size_t)row0 * DIM);
        #pragma unroll
        for (int p = 0; p < 4; ++p) {
            int li = p * 256 + t;
            int r = li >> 4;        // token within tile
            int c4 = li & 15;       // float4 chunk of dim
            float4 v = zg[r * (DIM / 4) + c4];
            zs[c4 * 4 + 0][r] = v.x;
            zs[c4 * 4 + 1][r] = v.y;
            zs[c4 * 4 + 2][r] = v.z;
            zs[c4 * 4 + 3][r] = v.w;
        }
    }
    __syncthreads();
    if (t < BM) {                    // z_sq per token (order irrelevant for argmin)
        float s = 0.f;
        for (int k = 0; k < DIM; ++k) { float v = zs[k][t]; s += v * v; }
        zsq_s[t] = s;
    }
    __syncthreads();

    const int tx = t & 31;           // code group: 32 x 4 codes = 128
    const int ty = t >> 5;           // token group: 8 x 8 tokens = 64

    float zsq_r[8];
    #pragma unroll
    for (int m = 0; m < 8; ++m) zsq_r[m] = zsq_s[ty * 8 + m];

    float best_d[8];
    int   best_i[8];
    #pragma unroll
    for (int m = 0; m < 8; ++m) { best_d[m] = 3.4e38f; best_i[m] = 0; }

    for (int tt = 0; tt < KCODES / BN; ++tt) {   // ascending code tiles
        const float4* eg = (const float4*)(E + (size_t)tt * BN * DIM);
        #pragma unroll
        for (int p = 0; p < 8; ++p) {
            int li = p * 256 + t;
            int c  = li >> 4;
            int k4 = li & 15;
            float4 v = eg[c * (DIM / 4) + k4];
            es[k4 * 4 + 0][c] = v.x;
            es[k4 * 4 + 1][c] = v.y;
            es[k4 * 4 + 2][c] = v.z;
            es[k4 * 4 + 3][c] = v.w;
        }
        __syncthreads();

        float acc[8][4];
        #pragma unroll
        for (int m = 0; m < 8; ++m)
            #pragma unroll
            for (int n = 0; n < 4; ++n) acc[m][n] = 0.f;

        #pragma unroll 4
        for (int k = 0; k < DIM; ++k) {          // sequential fp32 FMA over K
            float b[4], a[8];
            #pragma unroll
            for (int n = 0; n < 4; ++n) b[n] = es[k][tx * 4 + n];
            #pragma unroll
            for (int m = 0; m < 8; ++m) a[m] = zs[k][ty * 8 + m];
            #pragma unroll
            for (int m = 0; m < 8; ++m)
                #pragma unroll
                for (int n = 0; n < 4; ++n) acc[m][n] += a[m] * b[n];
        }

        float esq_r[4];
        #pragma unroll
        for (int n = 0; n < 4; ++n) esq_r[n] = esq[tt * BN + tx * 4 + n];

        #pragma unroll
        for (int m = 0; m < 8; ++m) {
            #pragma unroll
            for (int n = 0; n < 4; ++n) {        // ascending code index, strict <
                float d = (zsq_r[m] - 2.0f * acc[m][n]) + esq_r[n];
                int ci = tt * BN + tx * 4 + n;
                if (d < best_d[m]) { best_d[m] = d; best_i[m] = ci; }
            }
        }
        __syncthreads();
    }

    // reduce over the 32 lanes sharing this token group; ties -> smaller index
    #pragma unroll
    for (int m = 0; m < 8; ++m) {
        for (int off = 16; off >= 1; off >>= 1) {
            float od = __shfl_xor(best_d[m], off);
            int   oi = __shfl_xor(best_i[m], off);
            if (od < best_d[m] || (od == best_d[m] && oi < best_i[m])) {
                best_d[m] = od; best_i[m] = oi;
            }
        }
    }
    if (tx == 0) {
        #pragma unroll
        for (int m = 0; m < 8; ++m)
            idx_out[row0 + ty * 8 + m] = (float)best_i[m];
    }
}

// ------------------------------- K2: gather z_q, write out0, loss partials
__global__ __launch_bounds__(256) void gather_kernel(
    const float* __restrict__ z, const float* __restrict__ E,
    const float* __restrict__ idx_f, float* __restrict__ out0,
    float* __restrict__ partials) {
    __shared__ float red[4];
    const int t = threadIdx.x;
    const int token = blockIdx.x * 16 + (t >> 4);
    const int part  = t & 15;

    int id = (int)idx_f[token];
    const float4* z4 = (const float4*)z;
    const float4* E4 = (const float4*)E;
    float4 zv = z4[(size_t)token * 16 + part];
    float4 ev = E4[(size_t)id * 16 + part];

    float dx = ev.x - zv.x, dy = ev.y - zv.y, dz = ev.z - zv.z, dw = ev.w - zv.w;
    float4 o;
    o.x = zv.x + dx; o.y = zv.y + dy; o.z = zv.z + dz; o.w = zv.w + dw;
    ((float4*)out0)[(size_t)token * 16 + part] = o;

    float ls = dx * dx + dy * dy + dz * dz + dw * dw;
    #pragma unroll
    for (int off = 32; off >= 1; off >>= 1) ls += __shfl_xor(ls, off);
    if ((t & 63) == 0) red[t >> 6] = ls;
    __syncthreads();
    if (t == 0) partials[blockIdx.x] = red[0] + red[1] + red[2] + red[3];
}

// ------------------------------------------------------- K3: final loss
__global__ __launch_bounds__(256) void loss_kernel(
    const float* __restrict__ partials, int n, float* __restrict__ loss_out) {
    __shared__ float red[4];
    const int t = threadIdx.x;
    float s = 0.f;
    for (int i = t; i < n; i += 256) s += partials[i];
    #pragma unroll
    for (int off = 32; off >= 1; off >>= 1) s += __shfl_xor(s, off);
    if ((t & 63) == 0) red[t >> 6] = s;
    __syncthreads();
    if (t == 0) {
        float tot = red[0] + red[1] + red[2] + red[3];
        float m = tot / (float)(NTOK * DIM);
        loss_out[0] = m + 0.25f * m;
    }
}

extern "C" void kernel_launch(void* const* d_in, const int* in_sizes, int n_in,
                              void* d_out, int out_size, void* d_ws, size_t ws_size,
                              hipStream_t stream) {
    const float* z = (const float*)d_in[0];       // [131072, 64] f32
    const float* E = (const float*)d_in[1];       // [1024, 64] f32
    float* out = (float*)d_out;

    float* esq      = (float*)d_ws;               // 1024 floats
    float* partials = (float*)d_ws + 1024;        // 8192 floats

    esq_kernel<<<4, 256, 0, stream>>>(E, esq);
    argmin_kernel<<<NTOK / BM, 256, 0, stream>>>(z, E, esq, out + IDX_OFF);
    gather_kernel<<<NTOK / 16, 256, 0, stream>>>(z, E, out + IDX_OFF, out, partials);
    loss_kernel<<<1, 256, 0, stream>>>(partials, NTOK / 16, out + LOSS_OFF);
}

// Round 2
// 262.806 us; speedup vs baseline: 1.0192x; 1.0192x over previous
//
#include <hip/hip_runtime.h>

#define NTOK   131072
#define KCODES 1024
#define DIM    64
#define BM     64
#define BN     128

#define LOSS_OFF (NTOK * DIM)        // 8388608
#define IDX_OFF  (LOSS_OFF + 1)      // 8388609

// ---------------------------------------------------------------- K0: e_sq
__global__ __launch_bounds__(256) void esq_kernel(const float* __restrict__ E,
                                                  float* __restrict__ esq) {
    int c = blockIdx.x * blockDim.x + threadIdx.x;
    if (c < KCODES) {
        const float4* row = (const float4*)(E + c * DIM);
        float s = 0.f;
        #pragma unroll
        for (int i = 0; i < DIM / 4; ++i) {
            float4 v = row[i];
            s += v.x * v.x + v.y * v.y + v.z * v.z + v.w * v.w;
        }
        esq[c] = s;
    }
}

// ------------------------------------------------- K1: distances + argmin
// LDS: zs [64][64] transposed (16KB), es [64][128] transposed (32KB),
// esq_s 4KB. All inner-loop reads are ROW-contiguous float4 -> no padding
// needed, conflicts minimal. Total ~52.3KB -> 3 blocks/CU.
__global__ __launch_bounds__(256) void argmin_kernel(
    const float* __restrict__ z, const float* __restrict__ E,
    const float* __restrict__ esq, float* __restrict__ idx_out) {
    __shared__ __align__(16) float zs[DIM][BM];
    __shared__ __align__(16) float es[DIM][BN];
    __shared__ float zsq_s[BM];
    __shared__ __align__(16) float esq_s[KCODES];

    const int t = threadIdx.x;
    const int row0 = blockIdx.x * BM;

    // stage esq (1024 floats)
    #pragma unroll
    for (int p = 0; p < 4; ++p) esq_s[p * 256 + t] = esq[p * 256 + t];

    // stage z tile transposed [k][token]; coalesced global reads
    {
        const float4* zg = (const float4*)(z + (size_t)row0 * DIM);
        #pragma unroll
        for (int p = 0; p < 4; ++p) {
            int li = p * 256 + t;
            int r  = li >> 4;        // token 0..63
            int c4 = li & 15;        // float4 chunk of dim
            float4 v = zg[r * 16 + c4];
            zs[c4 * 4 + 0][r] = v.x;
            zs[c4 * 4 + 1][r] = v.y;
            zs[c4 * 4 + 2][r] = v.z;
            zs[c4 * 4 + 3][r] = v.w;
        }
    }
    __syncthreads();
    if (t < BM) {                    // z_sq per token
        float s = 0.f;
        for (int k = 0; k < DIM; ++k) { float v = zs[k][t]; s += v * v; }
        zsq_s[t] = s;
    }
    __syncthreads();

    const int tx = t & 31;           // 32 x 4 codes = 128
    const int ty = t >> 5;           // 8 x 8 tokens = 64

    float zsq_r[8];
    #pragma unroll
    for (int m = 0; m < 8; ++m) zsq_r[m] = zsq_s[ty * 8 + m];

    float best_d[8];
    int   best_i[8];
    #pragma unroll
    for (int m = 0; m < 8; ++m) { best_d[m] = 3.4e38f; best_i[m] = 0; }

    for (int tt = 0; tt < KCODES / BN; ++tt) {   // ascending code tiles
        // stage es transposed [k][code]; LDS writes are 2-way (free):
        // bank = code&31, 64 consecutive codes per wave.
        const float4* eg = (const float4*)(E + (size_t)tt * BN * DIM);
        #pragma unroll
        for (int p = 0; p < 8; ++p) {
            int li = p * 256 + t;
            int c  = li & 127;       // code within tile
            int k4 = li >> 7;        // 0..15 float4 chunk of dim
            float4 v = eg[c * 16 + k4];
            es[k4 * 4 + 0][c] = v.x;
            es[k4 * 4 + 1][c] = v.y;
            es[k4 * 4 + 2][c] = v.z;
            es[k4 * 4 + 3][c] = v.w;
        }
        __syncthreads();

        float acc[8][4];
        #pragma unroll
        for (int m = 0; m < 8; ++m)
            #pragma unroll
            for (int n = 0; n < 4; ++n) acc[m][n] = 0.f;

        #pragma unroll 8
        for (int k = 0; k < DIM; ++k) {          // sequential fp32 FMA over K
            float4 b4 = *(const float4*)&es[k][tx * 4];
            float4 a0 = *(const float4*)&zs[k][ty * 8 + 0];
            float4 a1 = *(const float4*)&zs[k][ty * 8 + 4];
            float a[8] = {a0.x, a0.y, a0.z, a0.w, a1.x, a1.y, a1.z, a1.w};
            float b[4] = {b4.x, b4.y, b4.z, b4.w};
            #pragma unroll
            for (int m = 0; m < 8; ++m)
                #pragma unroll
                for (int n = 0; n < 4; ++n) acc[m][n] += a[m] * b[n];
        }

        float4 e4 = *(const float4*)&esq_s[tt * BN + tx * 4];
        float esq_r[4] = {e4.x, e4.y, e4.z, e4.w};

        #pragma unroll
        for (int m = 0; m < 8; ++m) {
            #pragma unroll
            for (int n = 0; n < 4; ++n) {        // ascending code index, strict <
                float d = (zsq_r[m] - 2.0f * acc[m][n]) + esq_r[n];
                int ci = tt * BN + tx * 4 + n;
                if (d < best_d[m]) { best_d[m] = d; best_i[m] = ci; }
            }
        }
        __syncthreads();
    }

    // reduce over the 32 lanes sharing this token group; ties -> smaller index
    #pragma unroll
    for (int m = 0; m < 8; ++m) {
        for (int off = 16; off >= 1; off >>= 1) {
            float od = __shfl_xor(best_d[m], off);
            int   oi = __shfl_xor(best_i[m], off);
            if (od < best_d[m] || (od == best_d[m] && oi < best_i[m])) {
                best_d[m] = od; best_i[m] = oi;
            }
        }
    }
    if (tx == 0) {
        #pragma unroll
        for (int m = 0; m < 8; ++m)
            idx_out[row0 + ty * 8 + m] = (float)best_i[m];
    }
}

// ------------------------------- K2: gather z_q, write out0, loss partials
__global__ __launch_bounds__(256) void gather_kernel(
    const float* __restrict__ z, const float* __restrict__ E,
    const float* __restrict__ idx_f, float* __restrict__ out0,
    float* __restrict__ partials) {
    __shared__ float red[4];
    const int t = threadIdx.x;
    const int token = blockIdx.x * 16 + (t >> 4);
    const int part  = t & 15;

    int id = (int)idx_f[token];
    const float4* z4 = (const float4*)z;
    const float4* E4 = (const float4*)E;
    float4 zv = z4[(size_t)token * 16 + part];
    float4 ev = E4[(size_t)id * 16 + part];

    float dx = ev.x - zv.x, dy = ev.y - zv.y, dz = ev.z - zv.z, dw = ev.w - zv.w;
    float4 o;
    o.x = zv.x + dx; o.y = zv.y + dy; o.z = zv.z + dz; o.w = zv.w + dw;
    ((float4*)out0)[(size_t)token * 16 + part] = o;

    float ls = dx * dx + dy * dy + dz * dz + dw * dw;
    #pragma unroll
    for (int off = 32; off >= 1; off >>= 1) ls += __shfl_xor(ls, off);
    if ((t & 63) == 0) red[t >> 6] = ls;
    __syncthreads();
    if (t == 0) partials[blockIdx.x] = red[0] + red[1] + red[2] + red[3];
}

// ------------------------------------------------------- K3: final loss
__global__ __launch_bounds__(256) void loss_kernel(
    const float* __restrict__ partials, int n, float* __restrict__ loss_out) {
    __shared__ float red[4];
    const int t = threadIdx.x;
    float s = 0.f;
    for (int i = t; i < n; i += 256) s += partials[i];
    #pragma unroll
    for (int off = 32; off >= 1; off >>= 1) s += __shfl_xor(s, off);
    if ((t & 63) == 0) red[t >> 6] = s;
    __syncthreads();
    if (t == 0) {
        float tot = red[0] + red[1] + red[2] + red[3];
        float m = tot / (float)(NTOK * DIM);
        loss_out[0] = m + 0.25f * m;
    }
}

extern "C" void kernel_launch(void* const* d_in, const int* in_sizes, int n_in,
                              void* d_out, int out_size, void* d_ws, size_t ws_size,
                              hipStream_t stream) {
    const float* z = (const float*)d_in[0];       // [131072, 64] f32
    const float* E = (const float*)d_in[1];       // [1024, 64] f32
    float* out = (float*)d_out;

    float* esq      = (float*)d_ws;               // 1024 floats
    float* partials = (float*)d_ws + 1024;        // 8192 floats

    esq_kernel<<<4, 256, 0, stream>>>(E, esq);
    argmin_kernel<<<NTOK / BM, 256, 0, stream>>>(z, E, esq, out + IDX_OFF);
    gather_kernel<<<NTOK / 16, 256, 0, stream>>>(z, E, out + IDX_OFF, out, partials);
    loss_kernel<<<1, 256, 0, stream>>>(partials, NTOK / 16, out + LOSS_OFF);
}

// Round 3
// 256.614 us; speedup vs baseline: 1.0438x; 1.0241x over previous
//
#include <hip/hip_runtime.h>

#define NTOK   131072
#define KCODES 1024
#define DIM    64
#define BM     128
#define BN     128
#define NTILES (KCODES / BN)

#define LOSS_OFF (NTOK * DIM)        // 8388608
#define IDX_OFF  (LOSS_OFF + 1)      // 8388609

// ---------------------------------------------------------------- K0: e_sq
__global__ __launch_bounds__(256) void esq_kernel(const float* __restrict__ E,
                                                  float* __restrict__ esq) {
    int c = blockIdx.x * blockDim.x + threadIdx.x;
    if (c < KCODES) {
        const float4* row = (const float4*)(E + c * DIM);
        float s = 0.f;
        #pragma unroll
        for (int i = 0; i < DIM / 4; ++i) {
            float4 v = row[i];
            s += v.x * v.x + v.y * v.y + v.z * v.z + v.w * v.w;
        }
        esq[c] = s;
    }
}

// ------------------------------------------------- K1: distances + argmin
// BM=128 tokens x BN=128 codes per tile, 8x8 per-thread register tile.
// tx = t&15 owns codes tx*8..tx*8+7 (ascending), ty = t>>4 owns tokens
// ty*8..ty*8+7. es-tile for step tt+1 is prefetched into registers during
// step tt's compute (issue-early / write-late).
__global__ __launch_bounds__(256) void argmin_kernel(
    const float* __restrict__ z, const float* __restrict__ E,
    const float* __restrict__ esq, float* __restrict__ idx_out) {
    __shared__ __align__(16) float zs[DIM][BM];    // 32 KB, [k][token]
    __shared__ __align__(16) float es[DIM][BN];    // 32 KB, [k][code]
    __shared__ __align__(16) float esq_s[KCODES];  // 4 KB
    __shared__ float zsq_s[BM];

    const int t = threadIdx.x;
    const int row0 = blockIdx.x * BM;

    // stage esq
    #pragma unroll
    for (int p = 0; p < 4; ++p) esq_s[p * 256 + t] = esq[p * 256 + t];

    // stage z tile transposed [k][token]; global reads perfectly coalesced
    {
        const float4* zg = (const float4*)(z + (size_t)row0 * DIM);
        #pragma unroll
        for (int p = 0; p < 8; ++p) {
            int li = p * 256 + t;
            int r  = li >> 4;        // token 0..127
            int c4 = li & 15;        // float4 chunk of dim
            float4 v = zg[li];
            zs[c4 * 4 + 0][r] = v.x;
            zs[c4 * 4 + 1][r] = v.y;
            zs[c4 * 4 + 2][r] = v.z;
            zs[c4 * 4 + 3][r] = v.w;
        }
    }
    // stage es tile 0 transposed [k][code]; LDS writes 2-way (free)
    {
        const float4* eg = (const float4*)E;
        #pragma unroll
        for (int p = 0; p < 8; ++p) {
            int li = p * 256 + t;
            int c  = li & 127;
            int k4 = li >> 7;
            float4 v = eg[c * 16 + k4];
            es[k4 * 4 + 0][c] = v.x;
            es[k4 * 4 + 1][c] = v.y;
            es[k4 * 4 + 2][c] = v.z;
            es[k4 * 4 + 3][c] = v.w;
        }
    }
    __syncthreads();
    if (t < BM) {                    // z_sq per token (order irrelevant for argmin)
        float s = 0.f;
        for (int k = 0; k < DIM; ++k) { float v = zs[k][t]; s += v * v; }
        zsq_s[t] = s;
    }
    __syncthreads();

    const int tx = t & 15;           // 16 x 8 codes = 128
    const int ty = t >> 4;           // 16 x 8 tokens = 128

    float zsq_r[8];
    #pragma unroll
    for (int m = 0; m < 8; ++m) zsq_r[m] = zsq_s[ty * 8 + m];

    float best_d[8];
    int   best_i[8];
    #pragma unroll
    for (int m = 0; m < 8; ++m) { best_d[m] = 3.4e38f; best_i[m] = 0; }

    for (int tt = 0; tt < NTILES; ++tt) {        // ascending code tiles
        // prefetch next es tile into registers (latency hides under compute)
        float4 pv[8];
        if (tt < NTILES - 1) {
            const float4* eg = (const float4*)(E + (size_t)(tt + 1) * BN * DIM);
            #pragma unroll
            for (int p = 0; p < 8; ++p) {
                int li = p * 256 + t;
                pv[p] = eg[(li & 127) * 16 + (li >> 7)];
            }
        }

        float acc[8][8];
        #pragma unroll
        for (int m = 0; m < 8; ++m)
            #pragma unroll
            for (int n = 0; n < 8; ++n) acc[m][n] = 0.f;

        #pragma unroll 8
        for (int k = 0; k < DIM; ++k) {          // sequential fp32 FMA over K
            float4 b0 = *(const float4*)&es[k][tx * 8 + 0];
            float4 b1 = *(const float4*)&es[k][tx * 8 + 4];
            float4 a0 = *(const float4*)&zs[k][ty * 8 + 0];
            float4 a1 = *(const float4*)&zs[k][ty * 8 + 4];
            float a[8] = {a0.x, a0.y, a0.z, a0.w, a1.x, a1.y, a1.z, a1.w};
            float b[8] = {b0.x, b0.y, b0.z, b0.w, b1.x, b1.y, b1.z, b1.w};
            #pragma unroll
            for (int m = 0; m < 8; ++m)
                #pragma unroll
                for (int n = 0; n < 8; ++n) acc[m][n] += a[m] * b[n];
        }

        float4 e40 = *(const float4*)&esq_s[tt * BN + tx * 8 + 0];
        float4 e41 = *(const float4*)&esq_s[tt * BN + tx * 8 + 4];
        float esq_r[8] = {e40.x, e40.y, e40.z, e40.w, e41.x, e41.y, e41.z, e41.w};

        #pragma unroll
        for (int m = 0; m < 8; ++m) {
            #pragma unroll
            for (int n = 0; n < 8; ++n) {        // ascending code index, strict <
                float d = (zsq_r[m] - 2.0f * acc[m][n]) + esq_r[n];
                int ci = tt * BN + tx * 8 + n;
                if (d < best_d[m]) { best_d[m] = d; best_i[m] = ci; }
            }
        }
        __syncthreads();                          // all done reading es
        if (tt < NTILES - 1) {                    // write-late staging
            #pragma unroll
            for (int p = 0; p < 8; ++p) {
                int li = p * 256 + t;
                int c  = li & 127;
                int k4 = li >> 7;
                es[k4 * 4 + 0][c] = pv[p].x;
                es[k4 * 4 + 1][c] = pv[p].y;
                es[k4 * 4 + 2][c] = pv[p].z;
                es[k4 * 4 + 3][c] = pv[p].w;
            }
        }
        __syncthreads();                          // es ready for next tile
    }

    // reduce over the 16 lanes (tx) sharing this token group; lanes hold
    // disjoint ascending code ranges; ties -> smaller index (lexicographic)
    #pragma unroll
    for (int m = 0; m < 8; ++m) {
        #pragma unroll
        for (int off = 8; off >= 1; off >>= 1) {
            float od = __shfl_xor(best_d[m], off);
            int   oi = __shfl_xor(best_i[m], off);
            if (od < best_d[m] || (od == best_d[m] && oi < best_i[m])) {
                best_d[m] = od; best_i[m] = oi;
            }
        }
    }
    if (tx == 0) {
        #pragma unroll
        for (int m = 0; m < 8; ++m)
            idx_out[row0 + ty * 8 + m] = (float)best_i[m];
    }
}

// ------------------------------- K2: gather z_q, write out0, loss partials
__global__ __launch_bounds__(256) void gather_kernel(
    const float* __restrict__ z, const float* __restrict__ E,
    const float* __restrict__ idx_f, float* __restrict__ out0,
    float* __restrict__ partials) {
    __shared__ float red[4];
    const int t = threadIdx.x;
    const int token = blockIdx.x * 16 + (t >> 4);
    const int part  = t & 15;

    int id = (int)idx_f[token];
    const float4* z4 = (const float4*)z;
    const float4* E4 = (const float4*)E;
    float4 zv = z4[(size_t)token * 16 + part];
    float4 ev = E4[(size_t)id * 16 + part];

    float dx = ev.x - zv.x, dy = ev.y - zv.y, dz = ev.z - zv.z, dw = ev.w - zv.w;
    float4 o;
    o.x = zv.x + dx; o.y = zv.y + dy; o.z = zv.z + dz; o.w = zv.w + dw;
    ((float4*)out0)[(size_t)token * 16 + part] = o;

    float ls = dx * dx + dy * dy + dz * dz + dw * dw;
    #pragma unroll
    for (int off = 32; off >= 1; off >>= 1) ls += __shfl_xor(ls, off);
    if ((t & 63) == 0) red[t >> 6] = ls;
    __syncthreads();
    if (t == 0) partials[blockIdx.x] = red[0] + red[1] + red[2] + red[3];
}

// ------------------------------------------------------- K3: final loss
__global__ __launch_bounds__(256) void loss_kernel(
    const float* __restrict__ partials, int n, float* __restrict__ loss_out) {
    __shared__ float red[4];
    const int t = threadIdx.x;
    float s = 0.f;
    for (int i = t; i < n; i += 256) s += partials[i];
    #pragma unroll
    for (int off = 32; off >= 1; off >>= 1) s += __shfl_xor(s, off);
    if ((t & 63) == 0) red[t >> 6] = s;
    __syncthreads();
    if (t == 0) {
        float tot = red[0] + red[1] + red[2] + red[3];
        float m = tot / (float)(NTOK * DIM);
        loss_out[0] = m + 0.25f * m;
    }
}

extern "C" void kernel_launch(void* const* d_in, const int* in_sizes, int n_in,
                              void* d_out, int out_size, void* d_ws, size_t ws_size,
                              hipStream_t stream) {
    const float* z = (const float*)d_in[0];       // [131072, 64] f32
    const float* E = (const float*)d_in[1];       // [1024, 64] f32
    float* out = (float*)d_out;

    float* esq      = (float*)d_ws;               // 1024 floats
    float* partials = (float*)d_ws + 1024;        // 8192 floats

    esq_kernel<<<4, 256, 0, stream>>>(E, esq);
    argmin_kernel<<<NTOK / BM, 256, 0, stream>>>(z, E, esq, out + IDX_OFF);
    gather_kernel<<<NTOK / 16, 256, 0, stream>>>(z, E, out + IDX_OFF, out, partials);
    loss_kernel<<<1, 256, 0, stream>>>(partials, NTOK / 16, out + LOSS_OFF);
}